// Round 8
// baseline (732.634 us; speedup 1.0000x reference)
//
#include <hip/hip_runtime.h>
#include <hip/hip_cooperative_groups.h>

namespace cg = cooperative_groups;

constexpr int BB = 16;        // batch
constexpr int HH = 512;
constexpr int WW = 512;
constexpr int HW = HH * WW;   // 262144 = 2^18
constexpr int NP1 = BB * HW;  // one single-channel plane: 4,194,304 floats

// 11-tap Gaussian, theta=1, normalized (== normal pdf values to ~1e-8 rel).
__device__ constexpr float GK[11] = {
    1.4867195147342977e-06f,
    1.3383022576488537e-04f,
    4.4318484119380075e-03f,
    5.3990966513188063e-02f,
    2.4197072451914337e-01f,
    3.9894228040143270e-01f,
    2.4197072451914337e-01f,
    5.3990966513188063e-02f,
    4.4318484119380075e-03f,
    1.3383022576488537e-04f,
    1.4867195147342977e-06f,
};
// prefix sums of the smallest taps: PFX[k] = GK[0]+..+GK[k-1]
__device__ constexpr float PFX[6] = {
    0.0f,
    1.4867195147342977e-06f,
    1.3531694527962e-04f,
    4.5671653572176e-03f,
    5.8558131870406e-02f,
    3.0052885638955e-01f,
};

// blur(ones) separable factor with zero padding: missing taps at each edge
__device__ __forceinline__ float edgeS(int i) {
    float s = 1.f;
    if (i < 5)   s -= PFX[5 - i];
    if (i > 506) s -= PFX[i - 506];
    return s;
}

__device__ __forceinline__ float sig1(float d) {
    // q1 = e^d / (1 + e^d), clamped for overflow safety
    d = fminf(fmaxf(d, -30.f), 30.f);
    float e = __expf(d);
    return e * __builtin_amdgcn_rcpf(1.f + e);
}

// ===========================================================================
// PRIMARY: persistent cooperative kernel — conv + all 5 CRF iterations.
// 512 blocks x 256 threads = 2 blocks/CU co-resident (LDS 65.8 KB/block,
// VGPR cap 256 via launch bounds -> large margin on both).
// Block owns 16 rows x 512 px; thread owns an x-pair across those rows.
//   regs: du[16][2], d[16][2] (evolving state)
//   LDS : u0s[16][512] (epilogue), v[16][528] (hblur scratch, zero-padded)
// Per iteration: sigmoid own rows from regs + 10 halo rows from global
// (only boundary rows r<5 / r>=11 are ever written to dA/dB), vblur ->
// LDS -> hblur -> d update. grid.sync() + fences between iterations.
// ===========================================================================
__global__ __launch_bounds__(256, 2) void crf_fused(
    const float* __restrict__ x, const float* __restrict__ w,
    const float* __restrict__ bias, float* __restrict__ dA,
    float* __restrict__ dB, float* __restrict__ outp)
{
    __shared__ float u0s[16][512];
    __shared__ float v[16][528];

    cg::grid_group grid = cg::this_grid();

    int bid  = blockIdx.x;
    int tile = (bid & 7) * 64 + (bid >> 3);    // grid 512, bijective swizzle
    int b    = tile >> 5;                      // 32 tiles / image
    int y0   = (tile & 31) << 4;               // 16 owned rows
    int tid  = threadIdx.x;
    int x0   = tid << 1;                       // x-pair

    // zero hblur pads once (data writes only touch [5, 517))
    if (tid < 5) {
#pragma unroll
        for (int r = 0; r < 16; ++r) { v[r][tid] = 0.f; v[r][517 + tid] = 0.f; }
    }

    // ---------------- conv phase: u0/du for own 16 rows ----------------
    float W[54];
#pragma unroll
    for (int i = 0; i < 13; ++i)
        *(float4*)&W[4 * i] = *(const float4*)(w + 4 * i);
    W[52] = w[52];
    W[53] = w[53];
    float b0 = bias[0], b1 = bias[1];

    float a0[16][2], a1[16][2];
#pragma unroll
    for (int r = 0; r < 16; ++r) {
        a0[r][0] = b0; a0[r][1] = b0;
        a1[r][0] = b1; a1[r][1] = b1;
    }

    const float* xb = x + (size_t)b * 3 * HW;
#pragma unroll
    for (int iy = 0; iy < 18; ++iy) {          // input rows y0-1 .. y0+16
        int yy = y0 + iy - 1;
        if (yy < 0 || yy >= HH) continue;      // uniform
#pragma unroll
        for (int ci = 0; ci < 3; ++ci) {
            const float* rp = xb + ci * HW + yy * WW;
            float2 c = *(const float2*)(rp + x0);
            float l  = (x0 > 0)      ? rp[x0 - 1] : 0.f;
            float rr = (x0 + 2 < WW) ? rp[x0 + 2] : 0.f;
            float vv[4] = {l, c.x, c.y, rr};
#pragma unroll
            for (int kh = 0; kh < 3; ++kh) {
                int r = iy - kh;               // output row index
                if (r < 0 || r > 15) continue; // compile-time
                float w00 = W[ci * 9 + kh * 3 + 0];
                float w01 = W[ci * 9 + kh * 3 + 1];
                float w02 = W[ci * 9 + kh * 3 + 2];
                float w10 = W[27 + ci * 9 + kh * 3 + 0];
                float w11 = W[27 + ci * 9 + kh * 3 + 1];
                float w12 = W[27 + ci * 9 + kh * 3 + 2];
#pragma unroll
                for (int j = 0; j < 2; ++j) {
                    a0[r][j] = fmaf(w00, vv[j],
                               fmaf(w01, vv[j + 1],
                               fmaf(w02, vv[j + 2], a0[r][j])));
                    a1[r][j] = fmaf(w10, vv[j],
                               fmaf(w11, vv[j + 1],
                               fmaf(w12, vv[j + 2], a1[r][j])));
                }
            }
        }
    }

    float du[16][2], d[16][2];
    size_t pb = (size_t)b * HW + x0;
#pragma unroll
    for (int r = 0; r < 16; ++r) {
        u0s[r][x0]     = a0[r][0];
        u0s[r][x0 + 1] = a0[r][1];
        du[r][0] = a1[r][0] - a0[r][0];
        du[r][1] = a1[r][1] - a0[r][1];
        d[r][0] = du[r][0];
        d[r][1] = du[r][1];
        if (r < 5 || r >= 11)                  // boundary rows only
            *(float2*)(dA + pb + (size_t)(y0 + r) * WW) =
                make_float2(d[r][0], d[r][1]);
    }

    __threadfence();
    grid.sync();
    __threadfence();

    float SxA = edgeS(x0), SxB = edgeS(x0 + 1);

    // ---------------- 5 CRF iterations ----------------
    for (int k = 0; k < 5; ++k) {
        const float* src = (k & 1) ? dB : dA;
        float*       dst = (k & 1) ? dA : dB;

        float acc[16][2] = {{0.f}};
#pragma unroll
        for (int i = 0; i < 26; ++i) {         // rows y0-5 .. y0+20
            int yy = y0 + i - 5;
            if (yy < 0 || yy >= HH) continue;  // uniform
            float qa, qb;
            if (i >= 5 && i < 21) {            // own rows from regs
                qa = sig1(d[i - 5][0]);
                qb = sig1(d[i - 5][1]);
            } else {                           // halo rows from global
                float2 dv = *(const float2*)(src + pb + (size_t)yy * WW);
                qa = sig1(dv.x);
                qb = sig1(dv.y);
            }
#pragma unroll
            for (int r = 0; r < 16; ++r) {
                int dt = i - r;
                if (dt < 0 || dt > 10) continue;   // compile-time
                float kk = GK[dt];
                acc[r][0] = fmaf(kk, qa, acc[r][0]);
                acc[r][1] = fmaf(kk, qb, acc[r][1]);
            }
        }

        __syncthreads();                       // prev hblur reads done
#pragma unroll
        for (int r = 0; r < 16; ++r)
            *(float2*)(&v[r][5 + x0]) = make_float2(acc[r][0], acc[r][1]);
        __syncthreads();

#pragma unroll
        for (int r = 0; r < 16; ++r) {
            int yy = y0 + r;
            float Sy = edgeS(yy);

            float wv[12];
#pragma unroll
            for (int t = 0; t < 6; ++t)
                *(float2*)&wv[2 * t] = *(const float2*)(&v[r][x0 + 2 * t]);

            float m0 = 0.f, m1 = 0.f;
#pragma unroll
            for (int t = 0; t < 11; ++t) {
                m0 = fmaf(GK[t], wv[t], m0);
                m1 = fmaf(GK[t], wv[t + 1], m1);
            }

            float S0 = SxA * Sy, S1 = SxB * Sy;
            if (k == 4) {
                float ua = u0s[r][x0], ub = u0s[r][x0 + 1];
                size_t oo = (size_t)b * 2 * HW + (size_t)yy * WW + x0;
                *(float2*)(outp + oo) =
                    make_float2(ua + (S0 - m0), ub + (S1 - m1));
                *(float2*)(outp + oo + HW) =
                    make_float2((ua + du[r][0]) + m0, (ub + du[r][1]) + m1);
            } else {
                d[r][0] = du[r][0] + fmaf(2.f, m0, -S0);
                d[r][1] = du[r][1] + fmaf(2.f, m1, -S1);
                if (r < 5 || r >= 11)          // boundary rows only
                    *(float2*)(dst + pb + (size_t)yy * WW) =
                        make_float2(d[r][0], d[r][1]);
            }
        }

        if (k < 4) {
            __threadfence();
            grid.sync();
            __threadfence();
        }
    }
}

// ===========================================================================
// FALLBACK: proven multi-kernel pipeline (round-6 structure, ~94 µs)
// ===========================================================================
__global__ __launch_bounds__(256) void conv3x3_du(
    const float* __restrict__ x, const float* __restrict__ w,
    const float* __restrict__ bias, float* __restrict__ u0p,
    float* __restrict__ dup)
{
    int bid = blockIdx.x;
    int sb  = (bid & 7) * 128 + (bid >> 3);
    int t   = sb * 256 + threadIdx.x;
    int b   = t >> 14;
    int rem = t & 16383;
    int y0  = (rem >> 6) << 1;
    int xs  = (rem & 63) << 3;

    float W[54];
#pragma unroll
    for (int i = 0; i < 13; ++i)
        *(float4*)&W[4 * i] = *(const float4*)(w + 4 * i);
    W[52] = w[52];
    W[53] = w[53];
    float b0 = bias[0], b1 = bias[1];

    float acc0[2][8], acc1[2][8];
#pragma unroll
    for (int r = 0; r < 2; ++r)
#pragma unroll
        for (int j = 0; j < 8; ++j) { acc0[r][j] = b0; acc1[r][j] = b1; }

    const float* xb = x + (size_t)b * 3 * HW;
#pragma unroll
    for (int ci = 0; ci < 3; ++ci) {
        const float* xc = xb + ci * HW;
#pragma unroll
        for (int iy = 0; iy < 4; ++iy) {
            int yy = y0 - 1 + iy;
            if (yy < 0 || yy >= HH) continue;
            const float* r = xc + yy * WW;
            float4 cA = *(const float4*)(r + xs);
            float4 cB = *(const float4*)(r + xs + 4);
            float l  = (xs > 0)      ? r[xs - 1] : 0.f;
            float rr = (xs < WW - 8) ? r[xs + 8] : 0.f;
            float v[10] = {l, cA.x, cA.y, cA.z, cA.w,
                           cB.x, cB.y, cB.z, cB.w, rr};
#pragma unroll
            for (int orow = 0; orow < 2; ++orow) {
                int kh = iy - orow;
                if (kh < 0 || kh > 2) continue;
                float w00 = W[ci * 9 + kh * 3 + 0];
                float w01 = W[ci * 9 + kh * 3 + 1];
                float w02 = W[ci * 9 + kh * 3 + 2];
                float w10 = W[27 + ci * 9 + kh * 3 + 0];
                float w11 = W[27 + ci * 9 + kh * 3 + 1];
                float w12 = W[27 + ci * 9 + kh * 3 + 2];
#pragma unroll
                for (int j = 0; j < 8; ++j) {
                    acc0[orow][j] = fmaf(w00, v[j],
                                    fmaf(w01, v[j + 1],
                                    fmaf(w02, v[j + 2], acc0[orow][j])));
                    acc1[orow][j] = fmaf(w10, v[j],
                                    fmaf(w11, v[j + 1],
                                    fmaf(w12, v[j + 2], acc1[orow][j])));
                }
            }
        }
    }
#pragma unroll
    for (int orow = 0; orow < 2; ++orow) {
        size_t o = (size_t)b * HW + (size_t)(y0 + orow) * WW + xs;
        *(float4*)(u0p + o)     = make_float4(acc0[orow][0], acc0[orow][1],
                                              acc0[orow][2], acc0[orow][3]);
        *(float4*)(u0p + o + 4) = make_float4(acc0[orow][4], acc0[orow][5],
                                              acc0[orow][6], acc0[orow][7]);
        *(float4*)(dup + o)     = make_float4(acc1[orow][0] - acc0[orow][0],
                                              acc1[orow][1] - acc0[orow][1],
                                              acc1[orow][2] - acc0[orow][2],
                                              acc1[orow][3] - acc0[orow][3]);
        *(float4*)(dup + o + 4) = make_float4(acc1[orow][4] - acc0[orow][4],
                                              acc1[orow][5] - acc0[orow][5],
                                              acc1[orow][6] - acc0[orow][6],
                                              acc1[orow][7] - acc0[orow][7]);
    }
}

template <int MODE>
__global__ __launch_bounds__(256) void crf_diff2(
    const float* __restrict__ dcur, const float* __restrict__ dup,
    const float* __restrict__ u0p, float* __restrict__ outp)
{
    __shared__ float v[8][528];

    int bid  = blockIdx.x;
    int tile = (bid & 7) * 128 + (bid >> 3);
    int b    = tile >> 6;
    int y0   = (tile & 63) << 3;
    int tid  = threadIdx.x;
    int x0   = tid << 1;

    if (tid < 5) {
#pragma unroll
        for (int r = 0; r < 8; ++r) {
            v[r][tid] = 0.f;
            v[r][517 + tid] = 0.f;
        }
    }

    const float* dbase = dcur + (size_t)b * HW + x0;

    float acc[8][2] = {{0.f}};
    float2 raw[8];
#pragma unroll
    for (int i = 0; i < 18; ++i) {
        int yy = y0 + i - 5;
        if (yy < 0 || yy >= HH) continue;
        float2 dv = *(const float2*)(dbase + yy * WW);
        if (MODE == 0) {
            if (i >= 5 && i <= 12) raw[i - 5] = dv;
        }
        float qa = sig1(dv.x), qb = sig1(dv.y);
#pragma unroll
        for (int r = 0; r < 8; ++r) {
            int dt = i - r;
            if (dt < 0 || dt > 10) continue;
            float k = GK[dt];
            acc[r][0] = fmaf(k, qa, acc[r][0]);
            acc[r][1] = fmaf(k, qb, acc[r][1]);
        }
    }
#pragma unroll
    for (int r = 0; r < 8; ++r)
        *(float2*)(&v[r][5 + x0]) = make_float2(acc[r][0], acc[r][1]);
    __syncthreads();

    float SxA = edgeS(x0), SxB = edgeS(x0 + 1);

#pragma unroll
    for (int r = 0; r < 8; ++r) {
        int yy = y0 + r;
        float Sy = edgeS(yy);

        float wv[12];
#pragma unroll
        for (int t = 0; t < 6; ++t)
            *(float2*)&wv[2 * t] = *(const float2*)(&v[r][x0 + 2 * t]);

        float m0 = 0.f, m1 = 0.f;
#pragma unroll
        for (int t = 0; t < 11; ++t) {
            m0 = fmaf(GK[t], wv[t], m0);
            m1 = fmaf(GK[t], wv[t + 1], m1);
        }

        size_t po = (size_t)b * HW + (size_t)yy * WW + x0;
        float2 duv;
        if (MODE == 0) duv = raw[r];
        else           duv = *(const float2*)(dup + po);

        float S0 = SxA * Sy, S1 = SxB * Sy;
        if (MODE == 2) {
            float2 u0v = *(const float2*)(u0p + po);
            size_t oo = (size_t)b * 2 * HW + (size_t)yy * WW + x0;
            *(float2*)(outp + oo)      = make_float2(u0v.x + (S0 - m0),
                                                     u0v.y + (S1 - m1));
            *(float2*)(outp + oo + HW) = make_float2((u0v.x + duv.x) + m0,
                                                     (u0v.y + duv.y) + m1);
        } else {
            *(float2*)(outp + po) = make_float2(duv.x + fmaf(2.f, m0, -S0),
                                                duv.y + fmaf(2.f, m1, -S1));
        }
    }
}

extern "C" void kernel_launch(void* const* d_in, const int* in_sizes, int n_in,
                              void* d_out, int out_size, void* d_ws, size_t ws_size,
                              hipStream_t stream) {
    const float* x    = (const float*)d_in[0];   // (16,3,512,512)
    const float* w    = (const float*)d_in[1];   // (2,3,3,3)
    const float* bias = (const float*)d_in[2];   // (2,)

    float* out = (float*)d_out;                  // (16,2,512,512)
    float* dA  = (float*)d_ws;                   // coop halo buf A
    float* dB  = dA + NP1;                       // coop halo buf B

    void* args[] = {(void*)&x, (void*)&w, (void*)&bias,
                    (void*)&dA, (void*)&dB, (void*)&out};
    hipError_t e = hipLaunchCooperativeKernel((const void*)crf_fused,
                                              dim3(512), dim3(256), args,
                                              0, stream);
    if (e != hipSuccess) {
        // deterministic fallback: multi-kernel pipeline
        (void)hipGetLastError();                 // clear sticky error
        float* u0p = (float*)d_ws;
        float* dup = u0p + NP1;
        float* dA2 = dup + NP1;
        float* dB2 = dA2 + NP1;
        conv3x3_du<<<1024, 256, 0, stream>>>(x, w, bias, u0p, dup);
        crf_diff2<0><<<1024, 256, 0, stream>>>(dup, dup, u0p, dA2);
        crf_diff2<1><<<1024, 256, 0, stream>>>(dA2, dup, u0p, dB2);
        crf_diff2<1><<<1024, 256, 0, stream>>>(dB2, dup, u0p, dA2);
        crf_diff2<1><<<1024, 256, 0, stream>>>(dA2, dup, u0p, dB2);
        crf_diff2<2><<<1024, 256, 0, stream>>>(dB2, dup, u0p, out);
    }
}

// Round 9
// 145.617 us; speedup vs baseline: 5.0313x; 5.0313x over previous
//
#include <hip/hip_runtime.h>

constexpr int BB = 16;        // batch
constexpr int HH = 512;
constexpr int WW = 512;
constexpr int HW = HH * WW;   // 262144 = 2^18
constexpr int NP1 = BB * HW;  // one single-channel plane

// 11-tap Gaussian, theta=1, normalized (== normal pdf values to ~1e-8 rel).
__device__ constexpr float GK[11] = {
    1.4867195147342977e-06f,
    1.3383022576488537e-04f,
    4.4318484119380075e-03f,
    5.3990966513188063e-02f,
    2.4197072451914337e-01f,
    3.9894228040143270e-01f,
    2.4197072451914337e-01f,
    5.3990966513188063e-02f,
    4.4318484119380075e-03f,
    1.3383022576488537e-04f,
    1.4867195147342977e-06f,
};
// prefix sums of the smallest taps: PFX[k] = GK[0]+..+GK[k-1]
__device__ constexpr float PFX[6] = {
    0.0f,
    1.4867195147342977e-06f,
    1.3531694527962e-04f,
    4.5671653572176e-03f,
    5.8558131870406e-02f,
    3.0052885638955e-01f,
};

// blur(ones) separable factor with zero padding
__device__ __forceinline__ float edgeS(int i) {
    float s = 1.f;
    if (i < 5)   s -= PFX[5 - i];
    if (i > 506) s -= PFX[i - 506];
    return s;
}

__device__ __forceinline__ float sig1(float d) {
    d = fminf(fmaxf(d, -30.f), 30.f);
    float e = __expf(d);
    return e * __builtin_amdgcn_rcpf(1.f + e);
}

// ===========================================================================
// Kernel A: conv (C3->C2 3x3, zero-pad) + CRF it0, fused via halo recompute.
// Block owns 8 output rows; computes conv du for 18 intermediate rows
// (y0-5..y0+12) redundantly (x re-reads are L3 hits), then
// d1 = du + 2*blur(sig(du)) - S for its 8 rows.
// Writes u0p, dup (own 8 rows), d1 plane (own 8 rows).
// Thread owns an x-pair; 256 thr x 2 px = 512 px row width.
// ===========================================================================
__global__ __launch_bounds__(256, 4) void conv_it0(
    const float* __restrict__ x, const float* __restrict__ w,
    const float* __restrict__ bias, float* __restrict__ u0p,
    float* __restrict__ dup, float* __restrict__ d1p)
{
    __shared__ float v[8][528];

    int bid  = blockIdx.x;
    int tile = (bid & 7) * 128 + (bid >> 3);   // grid 1024, bijective swizzle
    int b    = tile >> 6;                      // 64 tiles / image
    int y0   = (tile & 63) << 3;               // 8 owned rows
    int tid  = threadIdx.x;
    int x0   = tid << 1;

    if (tid < 5) {
#pragma unroll
        for (int r = 0; r < 8; ++r) { v[r][tid] = 0.f; v[r][517 + tid] = 0.f; }
    }

    // weights -> (compiler puts these in SGPRs; uniform address)
    float W[54];
#pragma unroll
    for (int i = 0; i < 13; ++i)
        *(float4*)&W[4 * i] = *(const float4*)(w + 4 * i);
    W[52] = w[52];
    W[53] = w[53];
    float b0 = bias[0], b1 = bias[1];

    // conv accumulators for 18 intermediate rows (y0+r1-5), 2 px each
    float a0[18][2], a1[18][2];
#pragma unroll
    for (int r1 = 0; r1 < 18; ++r1) {
        a0[r1][0] = b0; a0[r1][1] = b0;
        a1[r1][0] = b1; a1[r1][1] = b1;
    }

    const float* xb = x + (size_t)b * 3 * HW;
#pragma unroll
    for (int iy = 0; iy < 20; ++iy) {          // input rows y0-6 .. y0+13
        int yy = y0 + iy - 6;
        if (yy < 0 || yy >= HH) continue;      // uniform
#pragma unroll
        for (int ci = 0; ci < 3; ++ci) {
            const float* rp = xb + ci * HW + yy * WW;
            float2 c = *(const float2*)(rp + x0);
            float l  = (x0 > 0)      ? rp[x0 - 1] : 0.f;
            float rr = (x0 + 2 < WW) ? rp[x0 + 2] : 0.f;
            float vv[4] = {l, c.x, c.y, rr};
#pragma unroll
            for (int kh = 0; kh < 3; ++kh) {
                int r1 = iy - kh;              // intermediate row index
                if (r1 < 0 || r1 > 17) continue;   // compile-time
                float w00 = W[ci * 9 + kh * 3 + 0];
                float w01 = W[ci * 9 + kh * 3 + 1];
                float w02 = W[ci * 9 + kh * 3 + 2];
                float w10 = W[27 + ci * 9 + kh * 3 + 0];
                float w11 = W[27 + ci * 9 + kh * 3 + 1];
                float w12 = W[27 + ci * 9 + kh * 3 + 2];
#pragma unroll
                for (int j = 0; j < 2; ++j) {
                    a0[r1][j] = fmaf(w00, vv[j],
                               fmaf(w01, vv[j + 1],
                               fmaf(w02, vv[j + 2], a0[r1][j])));
                    a1[r1][j] = fmaf(w10, vv[j],
                               fmaf(w11, vv[j + 1],
                               fmaf(w12, vv[j + 2], a1[r1][j])));
                }
            }
        }
    }

    size_t pb = (size_t)b * HW + x0;
    // write u0 / du for own 8 rows (r1 = 5..12)
#pragma unroll
    for (int r1 = 5; r1 < 13; ++r1) {
        int yy = y0 + r1 - 5;
        *(float2*)(u0p + pb + (size_t)yy * WW) =
            make_float2(a0[r1][0], a0[r1][1]);
        *(float2*)(dup + pb + (size_t)yy * WW) =
            make_float2(a1[r1][0] - a0[r1][0], a1[r1][1] - a0[r1][1]);
    }

    // it0 vblur: q = sig(du) over 18 intermediate rows -> 8 own rows
    float acc[8][2] = {{0.f}};
#pragma unroll
    for (int r1 = 0; r1 < 18; ++r1) {
        int yy = y0 + r1 - 5;
        if (yy < 0 || yy >= HH) continue;      // uniform
        float qa = sig1(a1[r1][0] - a0[r1][0]);
        float qb = sig1(a1[r1][1] - a0[r1][1]);
#pragma unroll
        for (int r = 0; r < 8; ++r) {
            int dt = r1 - r;
            if (dt < 0 || dt > 10) continue;   // compile-time
            float k = GK[dt];
            acc[r][0] = fmaf(k, qa, acc[r][0]);
            acc[r][1] = fmaf(k, qb, acc[r][1]);
        }
    }
#pragma unroll
    for (int r = 0; r < 8; ++r)
        *(float2*)(&v[r][5 + x0]) = make_float2(acc[r][0], acc[r][1]);
    __syncthreads();

    float SxA = edgeS(x0), SxB = edgeS(x0 + 1);
#pragma unroll
    for (int r = 0; r < 8; ++r) {
        int yy = y0 + r;
        float Sy = edgeS(yy);
        float wv[12];
#pragma unroll
        for (int t = 0; t < 6; ++t)
            *(float2*)&wv[2 * t] = *(const float2*)(&v[r][x0 + 2 * t]);
        float m0 = 0.f, m1 = 0.f;
#pragma unroll
        for (int t = 0; t < 11; ++t) {
            m0 = fmaf(GK[t], wv[t], m0);
            m1 = fmaf(GK[t], wv[t + 1], m1);
        }
        float dua = a1[r + 5][0] - a0[r + 5][0];
        float dub = a1[r + 5][1] - a0[r + 5][1];
        *(float2*)(d1p + pb + (size_t)yy * WW) =
            make_float2(dua + fmaf(2.f, m0, -(SxA * Sy)),
                        dub + fmaf(2.f, m1, -(SxB * Sy)));
    }
}

// ===========================================================================
// Kernel B: two fused CRF iterations (trapezoid).
//   mid  = du + 2*blur(sig(src)) - S   for 18 intermediate rows (regs)
//   outv = du + 2*blur(sig(mid)) - S   for 8 own rows      (FINAL=0)
//   out  = u0 +- (blur(sig(mid)) - S-part)  epilogue       (FINAL=1)
// Reads src slab rows y0-10..y0+17 (amp 3.5x, L2/L3-resident).
// LDS v[18][528] = 38 KB -> 4 blocks/CU.
// ===========================================================================
template <int FINAL>
__global__ __launch_bounds__(256, 4) void crf_pair(
    const float* __restrict__ sp, const float* __restrict__ dup,
    const float* __restrict__ u0p, float* __restrict__ outp)
{
    __shared__ float v[18][528];

    int bid  = blockIdx.x;
    int tile = (bid & 7) * 128 + (bid >> 3);   // grid 1024, bijective
    int b    = tile >> 6;
    int y0   = (tile & 63) << 3;
    int tid  = threadIdx.x;
    int x0   = tid << 1;

    if (tid < 5) {
#pragma unroll
        for (int r = 0; r < 18; ++r) { v[r][tid] = 0.f; v[r][517 + tid] = 0.f; }
    }

    size_t pb = (size_t)b * HW + x0;
    float SxA = edgeS(x0), SxB = edgeS(x0 + 1);

    // ---- stage A: vblur(sig(src)) for 18 intermediate rows ----
    float st[18][2] = {{0.f}};
#pragma unroll
    for (int i = 0; i < 28; ++i) {             // src rows y0-10 .. y0+17
        int yy = y0 + i - 10;
        if (yy < 0 || yy >= HH) continue;      // uniform
        float2 dv = *(const float2*)(sp + pb + (size_t)yy * WW);
        float qa = sig1(dv.x), qb = sig1(dv.y);
#pragma unroll
        for (int r1 = 0; r1 < 18; ++r1) {
            int dt = i - r1;
            if (dt < 0 || dt > 10) continue;   // compile-time
            float k = GK[dt];
            st[r1][0] = fmaf(k, qa, st[r1][0]);
            st[r1][1] = fmaf(k, qb, st[r1][1]);
        }
    }
#pragma unroll
    for (int r1 = 0; r1 < 18; ++r1)
        *(float2*)(&v[r1][5 + x0]) = make_float2(st[r1][0], st[r1][1]);
    __syncthreads();

    // ---- stage A hblur + mid update (in regs); capture du for own rows ----
    float duo[8][2];
#pragma unroll
    for (int r1 = 0; r1 < 18; ++r1) {
        int yy = y0 + r1 - 5;
        if (yy < 0 || yy >= HH) continue;      // uniform
        float wv[12];
#pragma unroll
        for (int t = 0; t < 6; ++t)
            *(float2*)&wv[2 * t] = *(const float2*)(&v[r1][x0 + 2 * t]);
        float m0 = 0.f, m1 = 0.f;
#pragma unroll
        for (int t = 0; t < 11; ++t) {
            m0 = fmaf(GK[t], wv[t], m0);
            m1 = fmaf(GK[t], wv[t + 1], m1);
        }
        float2 duv = *(const float2*)(dup + pb + (size_t)yy * WW);
        if (r1 >= 5 && r1 < 13) {
            duo[r1 - 5][0] = duv.x;
            duo[r1 - 5][1] = duv.y;
        }
        float Sy = edgeS(yy);
        st[r1][0] = duv.x + fmaf(2.f, m0, -(SxA * Sy));
        st[r1][1] = duv.y + fmaf(2.f, m1, -(SxB * Sy));
    }

    // ---- stage B: vblur(sig(mid)) for 8 own rows ----
    float acc[8][2] = {{0.f}};
#pragma unroll
    for (int r1 = 0; r1 < 18; ++r1) {
        int yy = y0 + r1 - 5;
        if (yy < 0 || yy >= HH) continue;      // uniform
        float qa = sig1(st[r1][0]), qb = sig1(st[r1][1]);
#pragma unroll
        for (int r = 0; r < 8; ++r) {
            int dt = r1 - r;
            if (dt < 0 || dt > 10) continue;   // compile-time
            float k = GK[dt];
            acc[r][0] = fmaf(k, qa, acc[r][0]);
            acc[r][1] = fmaf(k, qb, acc[r][1]);
        }
    }
    __syncthreads();                           // stage-A reads all done
#pragma unroll
    for (int r = 0; r < 8; ++r)
        *(float2*)(&v[r][5 + x0]) = make_float2(acc[r][0], acc[r][1]);
    __syncthreads();

#pragma unroll
    for (int r = 0; r < 8; ++r) {
        int yy = y0 + r;
        float Sy = edgeS(yy);
        float wv[12];
#pragma unroll
        for (int t = 0; t < 6; ++t)
            *(float2*)&wv[2 * t] = *(const float2*)(&v[r][x0 + 2 * t]);
        float m0 = 0.f, m1 = 0.f;
#pragma unroll
        for (int t = 0; t < 11; ++t) {
            m0 = fmaf(GK[t], wv[t], m0);
            m1 = fmaf(GK[t], wv[t + 1], m1);
        }
        float S0 = SxA * Sy, S1 = SxB * Sy;
        if (FINAL) {
            float2 u0v = *(const float2*)(u0p + pb + (size_t)yy * WW);
            size_t oo = (size_t)b * 2 * HW + (size_t)yy * WW + x0;
            *(float2*)(outp + oo) =
                make_float2(u0v.x + (S0 - m0), u0v.y + (S1 - m1));
            *(float2*)(outp + oo + HW) =
                make_float2((u0v.x + duo[r][0]) + m0,
                            (u0v.y + duo[r][1]) + m1);
        } else {
            *(float2*)(outp + pb + (size_t)yy * WW) =
                make_float2(duo[r][0] + fmaf(2.f, m0, -S0),
                            duo[r][1] + fmaf(2.f, m1, -S1));
        }
    }
}

extern "C" void kernel_launch(void* const* d_in, const int* in_sizes, int n_in,
                              void* d_out, int out_size, void* d_ws, size_t ws_size,
                              hipStream_t stream) {
    const float* x    = (const float*)d_in[0];   // (16,3,512,512)
    const float* w    = (const float*)d_in[1];   // (2,3,3,3)
    const float* bias = (const float*)d_in[2];   // (2,)

    float* out = (float*)d_out;                  // (16,2,512,512)
    float* u0p = (float*)d_ws;                   // 16.8 MB
    float* dup = u0p + NP1;                      // 16.8 MB
    float* dA  = dup + NP1;                      // 16.8 MB (d1)
    float* dB  = dA + NP1;                       // 16.8 MB (d3)

    conv_it0<<<1024, 256, 0, stream>>>(x, w, bias, u0p, dup, dA);   // it0
    crf_pair<0><<<1024, 256, 0, stream>>>(dA, dup, u0p, dB);        // it1+it2
    crf_pair<1><<<1024, 256, 0, stream>>>(dB, dup, u0p, out);       // it3+it4
}

// Round 10
// 106.580 us; speedup vs baseline: 6.8741x; 1.3663x over previous
//
#include <hip/hip_runtime.h>

constexpr int BB = 16;        // batch
constexpr int HH = 512;
constexpr int WW = 512;
constexpr int HW = HH * WW;   // 262144 = 2^18
constexpr int NP1 = BB * HW;  // one single-channel plane

// 11-tap Gaussian, theta=1, normalized (== normal pdf values to ~1e-8 rel).
__device__ constexpr float GK[11] = {
    1.4867195147342977e-06f,
    1.3383022576488537e-04f,
    4.4318484119380075e-03f,
    5.3990966513188063e-02f,
    2.4197072451914337e-01f,
    3.9894228040143270e-01f,
    2.4197072451914337e-01f,
    5.3990966513188063e-02f,
    4.4318484119380075e-03f,
    1.3383022576488537e-04f,
    1.4867195147342977e-06f,
};
// prefix sums of the smallest taps: PFX[k] = GK[0]+..+GK[k-1]
__device__ constexpr float PFX[6] = {
    0.0f,
    1.4867195147342977e-06f,
    1.3531694527962e-04f,
    4.5671653572176e-03f,
    5.8558131870406e-02f,
    3.0052885638955e-01f,
};

// blur(ones) separable factor with zero padding
__device__ __forceinline__ float edgeS(int i) {
    float s = 1.f;
    if (i < 5)   s -= PFX[5 - i];
    if (i > 506) s -= PFX[i - 506];
    return s;
}

__device__ __forceinline__ float sig1(float d) {
    d = fminf(fmaxf(d, -30.f), 30.f);
    float e = __expf(d);
    return e * __builtin_amdgcn_rcpf(1.f + e);
}

// ===========================================================================
// Kernel A: conv (C3->C2 3x3, zero-pad) + CRF it0, fused via halo recompute.
// ROLLING 3-ROW conv accumulators (12 floats live instead of 72 -> no spill):
// intermediate row r1 is fed by input rows iy = r1..r1+2; when iy finishes,
// row r1c = iy-2 is complete -> finalize (u0/du writes for own rows, sigmoid,
// vblur accumulate) and recycle its slot.
// Block owns 8 output rows (y0..y0+7); intermediate rows r1=0..17 are
// y0+r1-5; input rows iy=0..19 are y0+iy-6. Thread owns an x-pair.
// ===========================================================================
__global__ __launch_bounds__(256, 4) void conv_it0(
    const float* __restrict__ x, const float* __restrict__ w,
    const float* __restrict__ bias, float* __restrict__ u0p,
    float* __restrict__ dup, float* __restrict__ d1p)
{
    __shared__ float v[8][528];

    int bid  = blockIdx.x;
    int tile = (bid & 7) * 128 + (bid >> 3);   // grid 1024, bijective swizzle
    int b    = tile >> 6;                      // 64 tiles / image
    int y0   = (tile & 63) << 3;               // 8 owned rows
    int tid  = threadIdx.x;
    int x0   = tid << 1;

    if (tid < 5) {
#pragma unroll
        for (int r = 0; r < 8; ++r) { v[r][tid] = 0.f; v[r][517 + tid] = 0.f; }
    }

    // weights: uniform address -> scalar loads (SGPRs)
    float W[54];
#pragma unroll
    for (int i = 0; i < 13; ++i)
        *(float4*)&W[4 * i] = *(const float4*)(w + 4 * i);
    W[52] = w[52];
    W[53] = w[53];
    float b0 = bias[0], b1 = bias[1];

    // rolling conv accumulators: slot s holds intermediate row r1 with
    // r1 % 3 == s. ra*[s][j]
    float ra0[3][2], ra1[3][2];
#pragma unroll
    for (int s = 0; s < 3; ++s) {
        ra0[s][0] = b0; ra0[s][1] = b0;
        ra1[s][0] = b1; ra1[s][1] = b1;
    }

    float acc[8][2] = {{0.f}};   // it0 vblur accumulators (own rows)
    float duo[8][2];             // du of own rows (for d1 epilogue)

    const float* xb = x + (size_t)b * 3 * HW;
    size_t pb = (size_t)b * HW + x0;

#pragma unroll
    for (int iy = 0; iy < 20; ++iy) {          // input rows y0-6 .. y0+13
        int yy = y0 + iy - 6;
        if (yy >= 0 && yy < HH) {              // uniform branch
#pragma unroll
            for (int ci = 0; ci < 3; ++ci) {
                const float* rp = xb + ci * HW + yy * WW;
                float2 c = *(const float2*)(rp + x0);
                float l  = (x0 > 0)      ? rp[x0 - 1] : 0.f;
                float rr = (x0 + 2 < WW) ? rp[x0 + 2] : 0.f;
                float vv[4] = {l, c.x, c.y, rr};
#pragma unroll
                for (int kh = 0; kh < 3; ++kh) {
                    int r1 = iy - kh;          // intermediate row index
                    if (r1 < 0 || r1 > 17) continue;   // compile-time
                    constexpr int S3[3] = {0, 1, 2};
                    int s = S3[((iy % 3) - kh + 3) % 3]; // = r1 % 3, static
                    float w00 = W[ci * 9 + kh * 3 + 0];
                    float w01 = W[ci * 9 + kh * 3 + 1];
                    float w02 = W[ci * 9 + kh * 3 + 2];
                    float w10 = W[27 + ci * 9 + kh * 3 + 0];
                    float w11 = W[27 + ci * 9 + kh * 3 + 1];
                    float w12 = W[27 + ci * 9 + kh * 3 + 2];
#pragma unroll
                    for (int j = 0; j < 2; ++j) {
                        ra0[s][j] = fmaf(w00, vv[j],
                                    fmaf(w01, vv[j + 1],
                                    fmaf(w02, vv[j + 2], ra0[s][j])));
                        ra1[s][j] = fmaf(w10, vv[j],
                                    fmaf(w11, vv[j + 1],
                                    fmaf(w12, vv[j + 2], ra1[s][j])));
                    }
                }
            }
        }

        // finalize intermediate row r1c = iy - 2 (complete after input iy)
        {
            constexpr int LO = 2;              // iy >= 2 finalizes
            if (iy >= LO) {
                int r1c = iy - 2;              // 0..17, compile-time
                if (r1c <= 17) {
                    int s = r1c % 3;           // compile-time
                    int yo = y0 + r1c - 5;     // intermediate row y
                    // uniform validity: vblur zero-pad outside [0,HH)
                    if (yo >= 0 && yo < HH) {
                        float dua = ra1[s][0] - ra0[s][0];
                        float dub = ra1[s][1] - ra0[s][1];
                        if (r1c >= 5 && r1c < 13) {    // own row: write u0/du
                            *(float2*)(u0p + pb + (size_t)yo * WW) =
                                make_float2(ra0[s][0], ra0[s][1]);
                            *(float2*)(dup + pb + (size_t)yo * WW) =
                                make_float2(dua, dub);
                            duo[r1c - 5][0] = dua;
                            duo[r1c - 5][1] = dub;
                        }
                        float qa = sig1(dua), qb = sig1(dub);
#pragma unroll
                        for (int r = 0; r < 8; ++r) {
                            int dt = r1c - r;
                            if (dt < 0 || dt > 10) continue;  // compile-time
                            float k = GK[dt];
                            acc[r][0] = fmaf(k, qa, acc[r][0]);
                            acc[r][1] = fmaf(k, qb, acc[r][1]);
                        }
                    } else if (r1c >= 5 && r1c < 13) {
                        // own rows are always in range; keep compiler honest
                        duo[r1c - 5][0] = 0.f;
                        duo[r1c - 5][1] = 0.f;
                    }
                    // recycle slot for next row r1 = iy + 1 (same s)
                    ra0[s][0] = b0; ra0[s][1] = b0;
                    ra1[s][0] = b1; ra1[s][1] = b1;
                }
            }
        }
    }

    // it0 hblur + d1 write
#pragma unroll
    for (int r = 0; r < 8; ++r)
        *(float2*)(&v[r][5 + x0]) = make_float2(acc[r][0], acc[r][1]);
    __syncthreads();

    float SxA = edgeS(x0), SxB = edgeS(x0 + 1);
#pragma unroll
    for (int r = 0; r < 8; ++r) {
        int yy = y0 + r;
        float Sy = edgeS(yy);
        float wv[12];
#pragma unroll
        for (int t = 0; t < 6; ++t)
            *(float2*)&wv[2 * t] = *(const float2*)(&v[r][x0 + 2 * t]);
        float m0 = 0.f, m1 = 0.f;
#pragma unroll
        for (int t = 0; t < 11; ++t) {
            m0 = fmaf(GK[t], wv[t], m0);
            m1 = fmaf(GK[t], wv[t + 1], m1);
        }
        *(float2*)(d1p + pb + (size_t)yy * WW) =
            make_float2(duo[r][0] + fmaf(2.f, m0, -(SxA * Sy)),
                        duo[r][1] + fmaf(2.f, m1, -(SxB * Sy)));
    }
}

// ===========================================================================
// Kernel B: two fused CRF iterations (trapezoid). UNCHANGED from round 9
// (proven ~20 µs for 2 iterations).
// ===========================================================================
template <int FINAL>
__global__ __launch_bounds__(256, 4) void crf_pair(
    const float* __restrict__ sp, const float* __restrict__ dup,
    const float* __restrict__ u0p, float* __restrict__ outp)
{
    __shared__ float v[18][528];

    int bid  = blockIdx.x;
    int tile = (bid & 7) * 128 + (bid >> 3);   // grid 1024, bijective
    int b    = tile >> 6;
    int y0   = (tile & 63) << 3;
    int tid  = threadIdx.x;
    int x0   = tid << 1;

    if (tid < 5) {
#pragma unroll
        for (int r = 0; r < 18; ++r) { v[r][tid] = 0.f; v[r][517 + tid] = 0.f; }
    }

    size_t pb = (size_t)b * HW + x0;
    float SxA = edgeS(x0), SxB = edgeS(x0 + 1);

    // ---- stage A: vblur(sig(src)) for 18 intermediate rows ----
    float st[18][2] = {{0.f}};
#pragma unroll
    for (int i = 0; i < 28; ++i) {             // src rows y0-10 .. y0+17
        int yy = y0 + i - 10;
        if (yy < 0 || yy >= HH) continue;      // uniform
        float2 dv = *(const float2*)(sp + pb + (size_t)yy * WW);
        float qa = sig1(dv.x), qb = sig1(dv.y);
#pragma unroll
        for (int r1 = 0; r1 < 18; ++r1) {
            int dt = i - r1;
            if (dt < 0 || dt > 10) continue;   // compile-time
            float k = GK[dt];
            st[r1][0] = fmaf(k, qa, st[r1][0]);
            st[r1][1] = fmaf(k, qb, st[r1][1]);
        }
    }
#pragma unroll
    for (int r1 = 0; r1 < 18; ++r1)
        *(float2*)(&v[r1][5 + x0]) = make_float2(st[r1][0], st[r1][1]);
    __syncthreads();

    // ---- stage A hblur + mid update (in regs); capture du for own rows ----
    float duo[8][2];
#pragma unroll
    for (int r1 = 0; r1 < 18; ++r1) {
        int yy = y0 + r1 - 5;
        if (yy < 0 || yy >= HH) continue;      // uniform
        float wv[12];
#pragma unroll
        for (int t = 0; t < 6; ++t)
            *(float2*)&wv[2 * t] = *(const float2*)(&v[r1][x0 + 2 * t]);
        float m0 = 0.f, m1 = 0.f;
#pragma unroll
        for (int t = 0; t < 11; ++t) {
            m0 = fmaf(GK[t], wv[t], m0);
            m1 = fmaf(GK[t], wv[t + 1], m1);
        }
        float2 duv = *(const float2*)(dup + pb + (size_t)yy * WW);
        if (r1 >= 5 && r1 < 13) {
            duo[r1 - 5][0] = duv.x;
            duo[r1 - 5][1] = duv.y;
        }
        float Sy = edgeS(yy);
        st[r1][0] = duv.x + fmaf(2.f, m0, -(SxA * Sy));
        st[r1][1] = duv.y + fmaf(2.f, m1, -(SxB * Sy));
    }

    // ---- stage B: vblur(sig(mid)) for 8 own rows ----
    float acc[8][2] = {{0.f}};
#pragma unroll
    for (int r1 = 0; r1 < 18; ++r1) {
        int yy = y0 + r1 - 5;
        if (yy < 0 || yy >= HH) continue;      // uniform
        float qa = sig1(st[r1][0]), qb = sig1(st[r1][1]);
#pragma unroll
        for (int r = 0; r < 8; ++r) {
            int dt = r1 - r;
            if (dt < 0 || dt > 10) continue;   // compile-time
            float k = GK[dt];
            acc[r][0] = fmaf(k, qa, acc[r][0]);
            acc[r][1] = fmaf(k, qb, acc[r][1]);
        }
    }
    __syncthreads();                           // stage-A reads all done
#pragma unroll
    for (int r = 0; r < 8; ++r)
        *(float2*)(&v[r][5 + x0]) = make_float2(acc[r][0], acc[r][1]);
    __syncthreads();

#pragma unroll
    for (int r = 0; r < 8; ++r) {
        int yy = y0 + r;
        float Sy = edgeS(yy);
        float wv[12];
#pragma unroll
        for (int t = 0; t < 6; ++t)
            *(float2*)&wv[2 * t] = *(const float2*)(&v[r][x0 + 2 * t]);
        float m0 = 0.f, m1 = 0.f;
#pragma unroll
        for (int t = 0; t < 11; ++t) {
            m0 = fmaf(GK[t], wv[t], m0);
            m1 = fmaf(GK[t], wv[t + 1], m1);
        }
        float S0 = SxA * Sy, S1 = SxB * Sy;
        if (FINAL) {
            float2 u0v = *(const float2*)(u0p + pb + (size_t)yy * WW);
            size_t oo = (size_t)b * 2 * HW + (size_t)yy * WW + x0;
            *(float2*)(outp + oo) =
                make_float2(u0v.x + (S0 - m0), u0v.y + (S1 - m1));
            *(float2*)(outp + oo + HW) =
                make_float2((u0v.x + duo[r][0]) + m0,
                            (u0v.y + duo[r][1]) + m1);
        } else {
            *(float2*)(outp + pb + (size_t)yy * WW) =
                make_float2(duo[r][0] + fmaf(2.f, m0, -S0),
                            duo[r][1] + fmaf(2.f, m1, -S1));
        }
    }
}

extern "C" void kernel_launch(void* const* d_in, const int* in_sizes, int n_in,
                              void* d_out, int out_size, void* d_ws, size_t ws_size,
                              hipStream_t stream) {
    const float* x    = (const float*)d_in[0];   // (16,3,512,512)
    const float* w    = (const float*)d_in[1];   // (2,3,3,3)
    const float* bias = (const float*)d_in[2];   // (2,)

    float* out = (float*)d_out;                  // (16,2,512,512)
    float* u0p = (float*)d_ws;                   // 16.8 MB
    float* dup = u0p + NP1;                      // 16.8 MB
    float* dA  = dup + NP1;                      // 16.8 MB (d1)
    float* dB  = dA + NP1;                       // 16.8 MB (d3)

    conv_it0<<<1024, 256, 0, stream>>>(x, w, bias, u0p, dup, dA);   // it0
    crf_pair<0><<<1024, 256, 0, stream>>>(dA, dup, u0p, dB);        // it1+it2
    crf_pair<1><<<1024, 256, 0, stream>>>(dB, dup, u0p, out);       // it3+it4
}

// Round 11
// 78.426 us; speedup vs baseline: 9.3417x; 1.3590x over previous
//
#include <hip/hip_runtime.h>

constexpr int BB = 16;        // batch
constexpr int HH = 512;
constexpr int WW = 512;
constexpr int HW = HH * WW;   // 262144 = 2^18
constexpr int NP1 = BB * HW;  // one single-channel plane (elements)

using half_t = _Float16;
using half2v = __attribute__((ext_vector_type(2))) _Float16;
using half8v = __attribute__((ext_vector_type(8))) _Float16;

// 11-tap Gaussian, theta=1, normalized (== normal pdf values to ~1e-8 rel).
__device__ constexpr float GK[11] = {
    1.4867195147342977e-06f,
    1.3383022576488537e-04f,
    4.4318484119380075e-03f,
    5.3990966513188063e-02f,
    2.4197072451914337e-01f,
    3.9894228040143270e-01f,
    2.4197072451914337e-01f,
    5.3990966513188063e-02f,
    4.4318484119380075e-03f,
    1.3383022576488537e-04f,
    1.4867195147342977e-06f,
};
// prefix sums of the smallest taps: PFX[k] = GK[0]+..+GK[k-1]
__device__ constexpr float PFX[6] = {
    0.0f,
    1.4867195147342977e-06f,
    1.3531694527962e-04f,
    4.5671653572176e-03f,
    5.8558131870406e-02f,
    3.0052885638955e-01f,
};

// blur(ones) separable factor with zero padding
__device__ __forceinline__ float edgeS(int i) {
    float s = 1.f;
    if (i < 5)   s -= PFX[5 - i];
    if (i > 506) s -= PFX[i - 506];
    return s;
}

__device__ __forceinline__ float sig1(float d) {
    d = fminf(fmaxf(d, -30.f), 30.f);
    float e = __expf(d);
    return e * __builtin_amdgcn_rcpf(1.f + e);
}

// ---------------------------------------------------------------------------
// Kernel 1: 3x3 conv, C_in=3 -> C_out=2, SAME zero-pad (round-4 proven form:
// 2 output rows x 8 px per thread, weights hoisted, fp32 x loads via float4).
// Outputs u0 and du = u1-u0 as fp16 planes (half8v = one 16B store per row
// per plane).
// ---------------------------------------------------------------------------
__global__ __launch_bounds__(256) void conv3x3_du(
    const float* __restrict__ x, const float* __restrict__ w,
    const float* __restrict__ bias, half_t* __restrict__ u0p,
    half_t* __restrict__ dup)
{
    int bid = blockIdx.x;
    int sb  = (bid & 7) * 128 + (bid >> 3);     // grid 1024, bijective
    int t   = sb * 256 + threadIdx.x;
    int b   = t >> 14;                          // 16384 threads / image
    int rem = t & 16383;
    int y0  = (rem >> 6) << 1;                  // row pair 0,2,..,510
    int xs  = (rem & 63) << 3;                  // 8-px strip

    float W[54];
#pragma unroll
    for (int i = 0; i < 13; ++i)
        *(float4*)&W[4 * i] = *(const float4*)(w + 4 * i);
    W[52] = w[52];
    W[53] = w[53];
    float b0 = bias[0], b1 = bias[1];

    float acc0[2][8], acc1[2][8];
#pragma unroll
    for (int r = 0; r < 2; ++r)
#pragma unroll
        for (int j = 0; j < 8; ++j) { acc0[r][j] = b0; acc1[r][j] = b1; }

    const float* xb = x + (size_t)b * 3 * HW;
#pragma unroll
    for (int ci = 0; ci < 3; ++ci) {
        const float* xc = xb + ci * HW;
#pragma unroll
        for (int iy = 0; iy < 4; ++iy) {        // input rows y0-1 .. y0+2
            int yy = y0 - 1 + iy;
            if (yy < 0 || yy >= HH) continue;   // uniform
            const float* r = xc + yy * WW;
            float4 cA = *(const float4*)(r + xs);
            float4 cB = *(const float4*)(r + xs + 4);
            float l  = (xs > 0)      ? r[xs - 1] : 0.f;
            float rr = (xs < WW - 8) ? r[xs + 8] : 0.f;
            float v[10] = {l, cA.x, cA.y, cA.z, cA.w,
                           cB.x, cB.y, cB.z, cB.w, rr};
#pragma unroll
            for (int orow = 0; orow < 2; ++orow) {
                int kh = iy - orow;
                if (kh < 0 || kh > 2) continue;  // compile-time
                float w00 = W[ci * 9 + kh * 3 + 0];
                float w01 = W[ci * 9 + kh * 3 + 1];
                float w02 = W[ci * 9 + kh * 3 + 2];
                float w10 = W[27 + ci * 9 + kh * 3 + 0];
                float w11 = W[27 + ci * 9 + kh * 3 + 1];
                float w12 = W[27 + ci * 9 + kh * 3 + 2];
#pragma unroll
                for (int j = 0; j < 8; ++j) {
                    acc0[orow][j] = fmaf(w00, v[j],
                                    fmaf(w01, v[j + 1],
                                    fmaf(w02, v[j + 2], acc0[orow][j])));
                    acc1[orow][j] = fmaf(w10, v[j],
                                    fmaf(w11, v[j + 1],
                                    fmaf(w12, v[j + 2], acc1[orow][j])));
                }
            }
        }
    }
#pragma unroll
    for (int orow = 0; orow < 2; ++orow) {
        size_t o = (size_t)b * HW + (size_t)(y0 + orow) * WW + xs;
        half8v h0, h1;
#pragma unroll
        for (int j = 0; j < 8; ++j) {
            h0[j] = (half_t)acc0[orow][j];
            h1[j] = (half_t)(acc1[orow][j] - acc0[orow][j]);
        }
        *(half8v*)(u0p + o) = h0;   // 16B store (xs mult of 8 -> aligned)
        *(half8v*)(dup + o) = h1;
    }
}

// ---------------------------------------------------------------------------
// Kernel 2: one CRF iteration on the fp16 channel-difference state.
//   m = blur(sigmoid(d));  d' = du + 2*m - Sx*Sy
// MODE 0: dcur == du (first iteration); reuses in-flight du rows
// MODE 1: middle iteration
// MODE 2: final: out0 = u0 + SxSy - m ; out1 = u0 + du + m  (fp32 NCHW out)
// 8 output rows per block; 256 threads x 2 px (round-6 proven shape).
// Grid 1024; swizzle keeps each image's planes on one XCD across kernels.
// ---------------------------------------------------------------------------
template <int MODE>
__global__ __launch_bounds__(256) void crf_diff2(
    const half_t* __restrict__ dcur, const half_t* __restrict__ dup,
    const half_t* __restrict__ u0p, half_t* __restrict__ dnxt,
    float* __restrict__ outp)
{
    __shared__ float v[8][528];

    int bid  = blockIdx.x;
    int tile = (bid & 7) * 128 + (bid >> 3);   // grid 1024, bijective
    int b    = tile >> 6;                      // 64 tiles / image
    int y0   = (tile & 63) << 3;               // 8 output rows
    int tid  = threadIdx.x;
    int x0   = tid << 1;                       // 2 px per thread

    if (tid < 5) {
#pragma unroll
        for (int r = 0; r < 8; ++r) {
            v[r][tid] = 0.f;
            v[r][517 + tid] = 0.f;
        }
    }

    size_t pb = (size_t)b * HW + x0;

    float acc[8][2] = {{0.f}};
    float raw[8][2];                           // du rows for MODE0 epilogue
#pragma unroll
    for (int i = 0; i < 18; ++i) {             // input rows y0-5 .. y0+12
        int yy = y0 + i - 5;
        if (yy < 0 || yy >= HH) continue;      // uniform
        half2v dv = *(const half2v*)(dcur + pb + (size_t)yy * WW);
        float da = (float)dv[0], db_ = (float)dv[1];
        if (MODE == 0) {
            if (i >= 5 && i <= 12) { raw[i - 5][0] = da; raw[i - 5][1] = db_; }
        }
        float qa = sig1(da), qb = sig1(db_);
#pragma unroll
        for (int r = 0; r < 8; ++r) {
            int dt = i - r;
            if (dt < 0 || dt > 10) continue;   // compile-time
            float k = GK[dt];
            acc[r][0] = fmaf(k, qa, acc[r][0]);
            acc[r][1] = fmaf(k, qb, acc[r][1]);
        }
    }
#pragma unroll
    for (int r = 0; r < 8; ++r)
        *(float2*)(&v[r][5 + x0]) = make_float2(acc[r][0], acc[r][1]);
    __syncthreads();

    float SxA = edgeS(x0), SxB = edgeS(x0 + 1);

#pragma unroll
    for (int r = 0; r < 8; ++r) {
        int yy = y0 + r;
        float Sy = edgeS(yy);

        float wv[12];
#pragma unroll
        for (int t = 0; t < 6; ++t)
            *(float2*)&wv[2 * t] = *(const float2*)(&v[r][x0 + 2 * t]);

        float m0 = 0.f, m1 = 0.f;
#pragma unroll
        for (int t = 0; t < 11; ++t) {
            m0 = fmaf(GK[t], wv[t], m0);
            m1 = fmaf(GK[t], wv[t + 1], m1);
        }

        size_t po = pb + (size_t)yy * WW;
        float dua, dub;
        if (MODE == 0) { dua = raw[r][0]; dub = raw[r][1]; }
        else {
            half2v duv = *(const half2v*)(dup + po);
            dua = (float)duv[0]; dub = (float)duv[1];
        }

        float S0 = SxA * Sy, S1 = SxB * Sy;
        if (MODE == 2) {
            half2v u0v = *(const half2v*)(u0p + po);
            float ua = (float)u0v[0], ub = (float)u0v[1];
            size_t oo = (size_t)b * 2 * HW + (size_t)yy * WW + x0;
            *(float2*)(outp + oo)      = make_float2(ua + (S0 - m0),
                                                     ub + (S1 - m1));
            *(float2*)(outp + oo + HW) = make_float2((ua + dua) + m0,
                                                     (ub + dub) + m1);
        } else {
            half2v hw;
            hw[0] = (half_t)(dua + fmaf(2.f, m0, -S0));
            hw[1] = (half_t)(dub + fmaf(2.f, m1, -S1));
            *(half2v*)(dnxt + po) = hw;
        }
    }
}

extern "C" void kernel_launch(void* const* d_in, const int* in_sizes, int n_in,
                              void* d_out, int out_size, void* d_ws, size_t ws_size,
                              hipStream_t stream) {
    const float* x    = (const float*)d_in[0];   // (16,3,512,512)
    const float* w    = (const float*)d_in[1];   // (2,3,3,3)
    const float* bias = (const float*)d_in[2];   // (2,)

    float*  out = (float*)d_out;                 // (16,2,512,512) fp32
    half_t* u0p = (half_t*)d_ws;                 // 8.4 MB
    half_t* dup = u0p + NP1;                     // 8.4 MB
    half_t* dA  = dup + NP1;                     // 8.4 MB
    half_t* dB  = dA + NP1;                      // 8.4 MB

    conv3x3_du<<<1024, 256, 0, stream>>>(x, w, bias, u0p, dup);
    crf_diff2<0><<<1024, 256, 0, stream>>>(dup, dup, u0p, dA, out);  // it0
    crf_diff2<1><<<1024, 256, 0, stream>>>(dA,  dup, u0p, dB, out);  // it1
    crf_diff2<1><<<1024, 256, 0, stream>>>(dB,  dup, u0p, dA, out);  // it2
    crf_diff2<1><<<1024, 256, 0, stream>>>(dA,  dup, u0p, dB, out);  // it3
    crf_diff2<2><<<1024, 256, 0, stream>>>(dB,  dup, u0p, dA, out);  // it4
}